// Round 8
// baseline (4497.191 us; speedup 1.0000x reference)
//
#include <hip/hip_runtime.h>
#include <stdint.h>
#include <stddef.h>

typedef __attribute__((ext_vector_type(8))) short short8;
typedef __attribute__((ext_vector_type(4))) short short4_t;
typedef __attribute__((ext_vector_type(8))) unsigned short ushort8_t;
typedef __attribute__((ext_vector_type(4))) unsigned short ushort4_t;
typedef __attribute__((ext_vector_type(4))) float f32x4;
typedef __attribute__((ext_vector_type(4))) unsigned uint4_t;

// workspace layout (bytes)
#define XG_BYTES  (134217728ull)          // xg: [1024 t][4 g][1024 n][16 b] bf16
#define HS_BYTES  (33587200ull)           // hs: [1025 t][16 b][1024 k] bf16
#define PAD_OFF   (XG_BYTES + HS_BYTES)   // (unused, keeps offsets)
#define WT_OFF    (PAD_OFF + 32768ull)    // Wt: [9][1024 n][1024 k] bf16

#define SENT 0x7FC07FC0u                  // bf16 NaN pair — h is finite, never equals this

__device__ __forceinline__ unsigned short f2b(float f){
  unsigned u = __builtin_bit_cast(unsigned, f);
  u += 0x7fffu + ((u >> 16) & 1u);
  return (unsigned short)(u >> 16);
}
__device__ __forceinline__ float b2f(unsigned short b){
  unsigned u = ((unsigned)b) << 16;
  return __builtin_bit_cast(float, u);
}
__device__ __forceinline__ float sigm(float x){ return 1.0f / (1.0f + __expf(-x)); }
__device__ __forceinline__ float tanh_(float x){ return 2.0f / (1.0f + __expf(-2.0f*x)) - 1.0f; }

// ---- issue 8 dwordx4 from MALL (sc0 sc1), NO wait --------------------------
#define ISSUE_H8(p, a) asm volatile( \
    "global_load_dwordx4 %0, %8, off sc0 sc1\n\t" \
    "global_load_dwordx4 %1, %8, off offset:64 sc0 sc1\n\t" \
    "global_load_dwordx4 %2, %8, off offset:128 sc0 sc1\n\t" \
    "global_load_dwordx4 %3, %8, off offset:192 sc0 sc1\n\t" \
    "global_load_dwordx4 %4, %8, off offset:256 sc0 sc1\n\t" \
    "global_load_dwordx4 %5, %8, off offset:320 sc0 sc1\n\t" \
    "global_load_dwordx4 %6, %8, off offset:384 sc0 sc1\n\t" \
    "global_load_dwordx4 %7, %8, off offset:448 sc0 sc1" \
    : "=&v"(a[0]), "=&v"(a[1]), "=&v"(a[2]), "=&v"(a[3]), \
      "=&v"(a[4]), "=&v"(a[5]), "=&v"(a[6]), "=&v"(a[7]) \
    : "v"(p) : "memory")

// ---- issue 4 dwordx2 plain cached loads (xq), NO wait ----------------------
#define ISSUE_XQ(xb, x) asm volatile( \
    "global_load_dwordx2 %0, %4, off\n\t" \
    "global_load_dwordx2 %1, %5, off\n\t" \
    "global_load_dwordx2 %2, %6, off\n\t" \
    "global_load_dwordx2 %3, %7, off" \
    : "=&v"(x[0]), "=&v"(x[1]), "=&v"(x[2]), "=&v"(x[3]) \
    : "v"(xb), "v"((xb) + 16384), "v"((xb) + 32768), "v"((xb) + 49152) \
    : "memory")

__device__ __forceinline__ void st_u32_mall(unsigned* p, unsigned v){
  asm volatile("global_store_dword %0, %1, off sc0 sc1"
               :: "v"(p), "v"(v) : "memory");
}

// ---------------- weight transpose+convert: W[k][n] f32 -> Wt[n][k] bf16 ----
__global__ __launch_bounds__(256) void k_prep(
    const float* __restrict__ w0, const float* __restrict__ w1,
    const float* __restrict__ w2, const float* __restrict__ w3,
    const float* __restrict__ w4, const float* __restrict__ w5,
    const float* __restrict__ w6, const float* __restrict__ w7,
    const float* __restrict__ w8, unsigned short* __restrict__ wt)
{
  const int z = blockIdx.z;
  const float* W = (z==0)?w0:(z==1)?w1:(z==2)?w2:(z==3)?w3:(z==4)?w4:
                   (z==5)?w5:(z==6)?w6:(z==7)?w7:w8;
  unsigned short* out = wt + (size_t)z*1024*1024;
  __shared__ float tile[64][65];
  const int k0 = blockIdx.x*64, n0 = blockIdx.y*64;
  const int tid = threadIdx.x;
  {
    const int kk = tid >> 2, nn0 = (tid & 3) * 16;
    const float* src = W + (size_t)(k0+kk)*1024 + n0 + nn0;
    #pragma unroll
    for (int j=0;j<16;j+=4){
      f32x4 v = *(const f32x4*)(src + j);
      tile[kk][nn0+j+0]=v[0]; tile[kk][nn0+j+1]=v[1];
      tile[kk][nn0+j+2]=v[2]; tile[kk][nn0+j+3]=v[3];
    }
  }
  __syncthreads();
  {
    const int nn = tid >> 2, kk0 = (tid & 3) * 16;
    ushort8_t a, b;
    #pragma unroll
    for (int j=0;j<8;++j){ a[j]=f2b(tile[kk0+j][nn]); b[j]=f2b(tile[kk0+8+j][nn]); }
    unsigned short* dst = out + (size_t)(n0+nn)*1024 + k0 + kk0;
    *(ushort8_t*)dst = a;
    *(ushort8_t*)(dst+8) = b;
  }
}

// ---------------- h0 -> hs[0] bf16 ------------------------------------------
__global__ void k_init(const float* __restrict__ h0, unsigned short* __restrict__ hs){
  const int i = blockIdx.x*256 + threadIdx.x;
  hs[i] = f2b(h0[i]);
}

// ---------------- sentinel-fill hs[1..1024] ---------------------------------
__global__ void k_fill(unsigned* __restrict__ hsw){
  const size_t i = (size_t)blockIdx.x*256 + threadIdx.x;   // 2,097,152 threads
  uint4_t v = (uint4_t){SENT, SENT, SENT, SENT};
  *(uint4_t*)(hsw + 8192 + i*4) = v;                       // slot1 starts at word 8192
}

// ---------------- x projections: xg[t][g][n][b] = x @ Wx + bx (bf16 out) ----
__global__ __launch_bounds__(256,2) void k_xproj(
    const float* __restrict__ xF, const float* __restrict__ xI,
    const float* __restrict__ xZ, const float* __restrict__ xO,
    const float* __restrict__ bF, const float* __restrict__ bI,
    const float* __restrict__ bZ, const float* __restrict__ bO,
    const unsigned short* __restrict__ Wt,   // [4][n][k] bf16
    unsigned short* __restrict__ xg)
{
  const int g  = blockIdx.z;
  const int tm = blockIdx.x, tn = blockIdx.y;
  const float* X  = (g==0)?xF:(g==1)?xI:(g==2)?xZ:xO;
  const float* Bp = (g==0)?bF:(g==1)?bI:(g==2)?bZ:bO;
  const unsigned short* Wg = Wt + (size_t)g*1024*1024;

  __shared__ unsigned short Asm[128*32];
  __shared__ unsigned short Bsm[128*32];

  const int tid  = threadIdx.x;
  const int lane = tid & 63, wv = tid >> 6;
  const int l15  = lane & 15, lg = lane >> 4;
  const int wy   = wv >> 1,  wx = wv & 1;

  const int rr = tid >> 1, kq = tid & 1;
  const int ar = tm*128 + rr;
  const int ab = ar & 15, as_ = ar >> 4;
  const float* aptr = X + ((size_t)ab*1024 + as_)*1024 + kq*16;
  const unsigned short* bp_ = Wg + (size_t)(tn*128 + rr)*1024 + kq*16;
  const int s0 = kq*2;
  unsigned short* aw0 = &Asm[rr*32 + (((s0  ) ^ (rr&3))<<3)];
  unsigned short* aw1 = &Asm[rr*32 + (((s0+1) ^ (rr&3))<<3)];
  unsigned short* bw0 = &Bsm[rr*32 + (((s0  ) ^ (rr&3))<<3)];
  unsigned short* bw1 = &Bsm[rr*32 + (((s0+1) ^ (rr&3))<<3)];

  f32x4 acc[4][4];
  #pragma unroll
  for (int m=0;m<4;++m)
    #pragma unroll
    for (int q=0;q<4;++q) acc[m][q] = (f32x4){0.f,0.f,0.f,0.f};

  for (int k0=0; k0<1024; k0+=32){
    const float* ap = aptr + k0;
    f32x4 v0 = *(const f32x4*)(ap + 0);
    f32x4 v1 = *(const f32x4*)(ap + 4);
    f32x4 v2 = *(const f32x4*)(ap + 8);
    f32x4 v3 = *(const f32x4*)(ap + 12);
    ushort8_t pa, pb;
    #pragma unroll
    for (int j=0;j<4;++j){ pa[j]=f2b(v0[j]); pa[4+j]=f2b(v1[j]); pb[j]=f2b(v2[j]); pb[4+j]=f2b(v3[j]); }
    *(ushort8_t*)aw0 = pa;
    *(ushort8_t*)aw1 = pb;
    ushort8_t q0 = *(const ushort8_t*)(bp_ + k0);
    ushort8_t q1 = *(const ushort8_t*)(bp_ + k0 + 8);
    *(ushort8_t*)bw0 = q0;
    *(ushort8_t*)bw1 = q1;
    __syncthreads();

    short8 af[4], bf_[4];
    #pragma unroll
    for (int m=0;m<4;++m){
      int row = wy*64 + m*16 + l15;
      af[m] = *(const short8*)&Asm[row*32 + ((lg ^ (row&3))<<3)];
    }
    #pragma unroll
    for (int q=0;q<4;++q){
      int row = wx*64 + q*16 + l15;
      bf_[q] = *(const short8*)&Bsm[row*32 + ((lg ^ (row&3))<<3)];
    }
    #pragma unroll
    for (int m=0;m<4;++m)
      #pragma unroll
      for (int q=0;q<4;++q)
        acc[m][q] = __builtin_amdgcn_mfma_f32_16x16x32_bf16(af[m], bf_[q], acc[m][q], 0,0,0);
    __syncthreads();
  }

  #pragma unroll
  for (int m=0;m<4;++m){
    const int t = tm*8 + wy*4 + m;
    #pragma unroll
    for (int q=0;q<4;++q){
      const int n = tn*128 + wx*64 + q*16 + l15;
      const float bias = Bp[n];
      f32x4 v = acc[m][q];
      ushort4_t pk;
      #pragma unroll
      for (int r=0;r<4;++r) pk[r] = f2b(v[r] + bias);
      *(ushort4_t*)(xg + (size_t)((t*4+g)*1024 + n)*16 + lg*4) = pk;
    }
  }
}

// ---------------- persistent recurrence --------------------------------------
// 64 WGs; WG wg owns output cols [wg*16,+16); wave wv holds K-slice [wv*256,+256)
// in 128 weight VGPRs. Pipelined: issue spec h(t+1) + xq(t+1) right after MFMA;
// wait vmcnt(1) AFTER gating/store (loads retired, h-store still in flight).
// Sentinel retry reloads ONLY bad 16B chunks (exec-masked "+v"). No flags.
__global__ __launch_bounds__(256,1) void k_recur(
    const unsigned short* __restrict__ WtR,   // [4][1024 n][1024 k] bf16 (Fh,Ih,Zh,Oh)
    const float* __restrict__ bfh, const float* __restrict__ bih,
    const float* __restrict__ bzh, const float* __restrict__ boh,
    const float* __restrict__ c0,
    const unsigned short* __restrict__ xg,
    unsigned short* __restrict__ hs,
    float* __restrict__ oc, float* __restrict__ oh)
{
  const int wg   = blockIdx.x;          // 0..63
  const int tid  = threadIdx.x;
  const int wv   = tid >> 6, lane = tid & 63;
  const int l15  = lane & 15, lg = lane >> 4;
  const int n    = wg*16 + l15;
  const int row  = lg*4 + wv;           // the one batch row this lane gates
  const int sh   = wv * 16;             // component-extract shift for xq words

  // register-resident recurrent weights (pre-transposed bf16, coalesced)
  short8 wf[4][8];
  #pragma unroll
  for (int g=0; g<4; ++g){
    const unsigned short* wp = WtR + (size_t)g*1048576 + (size_t)n*1024 + wv*256 + lg*8;
    #pragma unroll
    for (int c=0; c<8; ++c)
      wf[g][c] = *(const short8*)(wp + c*32);
  }

  // gating state: single (row, col) per lane
  float cst = c0[(size_t)row*1024 + n];
  float bias0 = bfh[n], bias1 = bih[n], bias2 = bzh[n], bias3 = boh[n];

  // partials as component planes: [pb][wave][gate][comp][lane]  (32 KB)
  __shared__ float part[2][4][4][4][64];

  unsigned* hsw = (unsigned*)hs;
  const int koff = l15*1024 + wv*256 + lg*8;      // element offset within a t-slot

  short8 a[8];
  short4_t xq[4], xqn[4];

  // ---- prologue: issue spec h(0) + xq(0), drain, check (hs[0] is clean) ----
  {
    const unsigned short* hp = hs + koff;
    ISSUE_H8(hp, a);
    const unsigned short* xb = xg + ((size_t)n)*16 + lg*4;
    ISSUE_XQ(xb, xq);
    asm volatile("s_waitcnt vmcnt(0)" ::: "memory");
    __builtin_amdgcn_sched_barrier(0);
  }

  float hv = 0.f;
  for (int t=0; t<1024; ++t){
    // 1. MFMA: 4 gates x 8 K-chunks (consumes a[])
    f32x4 acc[4];
    #pragma unroll
    for (int g=0;g<4;++g) acc[g] = (f32x4){0.f,0.f,0.f,0.f};
    #pragma unroll
    for (int c=0;c<8;++c){
      acc[0] = __builtin_amdgcn_mfma_f32_16x16x32_bf16(a[c], wf[0][c], acc[0], 0,0,0);
      acc[1] = __builtin_amdgcn_mfma_f32_16x16x32_bf16(a[c], wf[1][c], acc[1], 0,0,0);
      acc[2] = __builtin_amdgcn_mfma_f32_16x16x32_bf16(a[c], wf[2][c], acc[2], 0,0,0);
      acc[3] = __builtin_amdgcn_mfma_f32_16x16x32_bf16(a[c], wf[3][c], acc[3], 0,0,0);
    }

    // 2. issue spec h(t+1) into a[] (a free after MFMA) + xq(t+1); no wait
    const unsigned short* hp1 = hs + (size_t)(t+1)*16384 + koff;
    ISSUE_H8(hp1, a);
    {
      const unsigned short* xb = xg + ((size_t)(t+1)*4096 + n)*16 + lg*4;
      ISSUE_XQ(xb, xqn);
    }

    // 3. partial store (component planes) + raw barrier (no VMEM drain)
    const int pb = t & 1;
    #pragma unroll
    for (int g=0;g<4;++g)
      #pragma unroll
      for (int cm=0;cm<4;++cm)
        part[pb][wv][g][cm][lane] = acc[g][cm];
    asm volatile("s_waitcnt lgkmcnt(0)" ::: "memory");
    __builtin_amdgcn_s_barrier();

    // 4. reduce only component wv (this lane's batch row), conflict-free
    float rg[4];
    #pragma unroll
    for (int g=0;g<4;++g)
      rg[g] = (part[pb][0][g][wv][lane] + part[pb][1][g][wv][lane])
            + (part[pb][2][g][wv][lane] + part[pb][3][g][wv][lane]);

    // 5. gate the single (row, col)
    {
      float pf = rg[0] + b2f((unsigned short)(__builtin_bit_cast(unsigned long long, xq[0]) >> sh)) + bias0;
      float pi = rg[1] + b2f((unsigned short)(__builtin_bit_cast(unsigned long long, xq[1]) >> sh)) + bias1;
      float pz = rg[2] + b2f((unsigned short)(__builtin_bit_cast(unsigned long long, xq[2]) >> sh)) + bias2;
      float po = rg[3] + b2f((unsigned short)(__builtin_bit_cast(unsigned long long, xq[3]) >> sh)) + bias3;
      float fg = sigm(pf), ig = sigm(pi), zg = tanh_(pz), og = sigm(po);
      float cn = fg*cst + ig*zg;
      cst = cn;
      hv = og * tanh_(cn);
    }

    // 6. pack bf16 pairs across lane^1; even lanes store 1 u32 (last VMEM op)
    {
      unsigned m  = (unsigned)f2b(hv);
      unsigned nb = (unsigned)__shfl_xor(m, 1);
      if ((l15 & 1) == 0){
        unsigned* pw = hsw + (size_t)(t+1)*8192 + (size_t)row*512 + (n >> 1);
        st_u32_mall(pw, m | (nb << 16));
      }
    }

    // 7. wait for the 12 loads (store may stay in flight), check, chunk-retry
    if (t < 1023){
      asm volatile("s_waitcnt vmcnt(1)" ::: "memory");
      __builtin_amdgcn_sched_barrier(0);
      bool bad[8]; bool any = false;
      #pragma unroll
      for (int c=0;c<8;++c){
        uint4_t q = __builtin_bit_cast(uint4_t, a[c]);
        bad[c] = (q[0]==SENT)||(q[1]==SENT)||(q[2]==SENT)||(q[3]==SENT);
        any = any | bad[c];
      }
      while (__any(any)){
        __builtin_amdgcn_s_sleep(1);
        #pragma unroll
        for (int c=0;c<8;++c)
          if (bad[c])
            asm volatile("global_load_dwordx4 %0, %1, off sc0 sc1"
                         : "+v"(a[c]) : "v"(hp1 + c*32) : "memory");
        asm volatile("s_waitcnt vmcnt(0)" ::: "memory");
        __builtin_amdgcn_sched_barrier(0);
        any = false;
        #pragma unroll
        for (int c=0;c<8;++c){
          uint4_t q = __builtin_bit_cast(uint4_t, a[c]);
          bad[c] = (q[0]==SENT)||(q[1]==SENT)||(q[2]==SENT)||(q[3]==SENT);
          any = any | bad[c];
        }
      }
      // 8. rotate xq pipeline (after the wait: xqn now valid)
      #pragma unroll
      for (int g=0; g<4; ++g) xq[g] = xqn[g];
    }
  }

  // final state: each lane owns one (row, col)
  oc[(size_t)row*1024 + n] = cst;
  oh[(size_t)row*1024 + n] = hv;
}

// ---------------- post projection: y[b][s][n] = hs[1..] @ Wpost + bpost -----
__global__ __launch_bounds__(256,2) void k_post(
    const unsigned short* __restrict__ hs,
    const unsigned short* __restrict__ Wt,   // post slice at +4M
    const float* __restrict__ bpost,
    float* __restrict__ y)
{
  const int tm = blockIdx.x, tn = blockIdx.y;
  __shared__ unsigned short Asm[128*32];
  __shared__ unsigned short Bsm[128*32];

  const int tid  = threadIdx.x;
  const int lane = tid & 63, wv = tid >> 6;
  const int l15  = lane & 15, lg = lane >> 4;
  const int wy   = wv >> 1,  wx = wv & 1;

  const int rr = tid >> 1, kq = tid & 1;
  const unsigned short* aptr = hs + 16384 + (size_t)(tm*128 + rr)*1024 + kq*16;
  const unsigned short* bp_  = Wt + (size_t)4*1024*1024 + (size_t)(tn*128 + rr)*1024 + kq*16;
  const int s0 = kq*2;
  unsigned short* aw0 = &Asm[rr*32 + (((s0  ) ^ (rr&3))<<3)];
  unsigned short* aw1 = &Asm[rr*32 + (((s0+1) ^ (rr&3))<<3)];
  unsigned short* bw0 = &Bsm[rr*32 + (((s0  ) ^ (rr&3))<<3)];
  unsigned short* bw1 = &Bsm[rr*32 + (((s0+1) ^ (rr&3))<<3)];

  f32x4 acc[4][4];
  #pragma unroll
  for (int m=0;m<4;++m)
    #pragma unroll
    for (int q=0;q<4;++q) acc[m][q] = (f32x4){0.f,0.f,0.f,0.f};

  for (int k0=0; k0<1024; k0+=32){
    ushort8_t a0 = *(const ushort8_t*)(aptr + k0);
    ushort8_t a1 = *(const ushort8_t*)(aptr + k0 + 8);
    *(ushort8_t*)aw0 = a0;
    *(ushort8_t*)aw1 = a1;
    ushort8_t q0 = *(const ushort8_t*)(bp_ + k0);
    ushort8_t q1 = *(const ushort8_t*)(bp_ + k0 + 8);
    *(ushort8_t*)bw0 = q0;
    *(ushort8_t*)bw1 = q1;
    __syncthreads();

    short8 af[4], bf_[4];
    #pragma unroll
    for (int m=0;m<4;++m){
      int row = wy*64 + m*16 + l15;
      af[m] = *(const short8*)&Asm[row*32 + ((lg ^ (row&3))<<3)];
    }
    #pragma unroll
    for (int q=0;q<4;++q){
      int row = wx*64 + q*16 + l15;
      bf_[q] = *(const short8*)&Bsm[row*32 + ((lg ^ (row&3))<<3)];
    }
    #pragma unroll
    for (int m=0;m<4;++m)
      #pragma unroll
      for (int q=0;q<4;++q)
        acc[m][q] = __builtin_amdgcn_mfma_f32_16x16x32_bf16(af[m], bf_[q], acc[m][q], 0,0,0);
    __syncthreads();
  }

  #pragma unroll
  for (int m=0;m<4;++m){
    const int s = tm*8 + wy*4 + m;
    #pragma unroll
    for (int q=0;q<4;++q){
      const int n = tn*128 + wx*64 + q*16 + l15;
      const float bias = bpost[n];
      f32x4 v = acc[m][q];
      #pragma unroll
      for (int r=0;r<4;++r){
        const int b = lg*4 + r;
        y[((size_t)b << 20) + ((size_t)s << 10) + n] = v[r] + bias;
      }
    }
  }
}

extern "C" void kernel_launch(void* const* d_in, const int* in_sizes, int n_in,
                              void* d_out, int out_size, void* d_ws, size_t ws_size,
                              hipStream_t stream)
{
  const float* f_in = (const float*)d_in[0];
  const float* i_in = (const float*)d_in[1];
  const float* z_in = (const float*)d_in[2];
  const float* o_in = (const float*)d_in[3];
  const float* c0   = (const float*)d_in[4];
  const float* h0   = (const float*)d_in[5];
  const float* W_Fx = (const float*)d_in[6];  const float* b_Fx = (const float*)d_in[7];
  const float* W_Ix = (const float*)d_in[8];  const float* b_Ix = (const float*)d_in[9];
  const float* W_Zx = (const float*)d_in[10]; const float* b_Zx = (const float*)d_in[11];
  const float* W_Ox = (const float*)d_in[12]; const float* b_Ox = (const float*)d_in[13];
  const float* W_Fh = (const float*)d_in[14]; const float* b_Fh = (const float*)d_in[15];
  const float* W_Ih = (const float*)d_in[16]; const float* b_Ih = (const float*)d_in[17];
  const float* W_Zh = (const float*)d_in[18]; const float* b_Zh = (const float*)d_in[19];
  const float* W_Oh = (const float*)d_in[20]; const float* b_Oh = (const float*)d_in[21];
  const float* W_post = (const float*)d_in[22]; const float* b_post = (const float*)d_in[23];

  char* ws = (char*)d_ws;
  unsigned short* xg    = (unsigned short*)(ws);
  unsigned short* hs    = (unsigned short*)(ws + XG_BYTES);
  unsigned short* wt    = (unsigned short*)(ws + WT_OFF);

  float* y  = (float*)d_out;
  float* oc = y + 16777216;   // 16*1024*1024
  float* oh = oc + 16384;

  k_prep<<<dim3(16,16,9), 256, 0, stream>>>(W_Fx, W_Ix, W_Zx, W_Ox, W_post,
                                            W_Fh, W_Ih, W_Zh, W_Oh, wt);
  k_init<<<64, 256, 0, stream>>>(h0, hs);
  k_fill<<<8192, 256, 0, stream>>>((unsigned*)hs);
  k_xproj<<<dim3(128,8,4), 256, 0, stream>>>(f_in, i_in, z_in, o_in,
                                             b_Fx, b_Ix, b_Zx, b_Ox, wt, xg);
  k_recur<<<64, 256, 0, stream>>>(wt + (size_t)5*1024*1024,
                                  b_Fh, b_Ih, b_Zh, b_Oh,
                                  c0, xg, hs, oc, oh);
  k_post<<<dim3(128,8), 256, 0, stream>>>(hs, wt, b_post, y);
}

// Round 9
// 4341.164 us; speedup vs baseline: 1.0359x; 1.0359x over previous
//
#include <hip/hip_runtime.h>
#include <stdint.h>
#include <stddef.h>

typedef __attribute__((ext_vector_type(8))) short short8;
typedef __attribute__((ext_vector_type(4))) short short4_t;
typedef __attribute__((ext_vector_type(8))) unsigned short ushort8_t;
typedef __attribute__((ext_vector_type(4))) unsigned short ushort4_t;
typedef __attribute__((ext_vector_type(4))) float f32x4;
typedef __attribute__((ext_vector_type(4))) unsigned uint4_t;

// workspace layout (bytes)
#define XG_BYTES  (134217728ull)          // xg: [1024 t][4 g][1024 n][16 b] bf16
#define HS_BYTES  (33587200ull)           // hs: [1025 t][16 b][1024 k] bf16
#define PAD_OFF   (XG_BYTES + HS_BYTES)   // (unused, keeps offsets)
#define WT_OFF    (PAD_OFF + 32768ull)    // Wt: [9][1024 n][1024 k] bf16

#define SENT 0x7FC07FC0u                  // bf16 NaN pair — h is finite, never equals this

__device__ __forceinline__ unsigned short f2b(float f){
  unsigned u = __builtin_bit_cast(unsigned, f);
  u += 0x7fffu + ((u >> 16) & 1u);
  return (unsigned short)(u >> 16);
}
__device__ __forceinline__ float b2f(unsigned short b){
  unsigned u = ((unsigned)b) << 16;
  return __builtin_bit_cast(float, u);
}
__device__ __forceinline__ float sigm(float x){ return 1.0f / (1.0f + __expf(-x)); }
__device__ __forceinline__ float tanh_(float x){ return 2.0f / (1.0f + __expf(-2.0f*x)) - 1.0f; }

// ---- issue 4 dwordx4 from MALL (sc0 sc1), NO wait --------------------------
#define ISSUE_H4(p, a) asm volatile( \
    "global_load_dwordx4 %0, %4, off sc0 sc1\n\t" \
    "global_load_dwordx4 %1, %4, off offset:64 sc0 sc1\n\t" \
    "global_load_dwordx4 %2, %4, off offset:128 sc0 sc1\n\t" \
    "global_load_dwordx4 %3, %4, off offset:192 sc0 sc1" \
    : "=&v"(a[0]), "=&v"(a[1]), "=&v"(a[2]), "=&v"(a[3]) \
    : "v"(p) : "memory")

// ---- issue 4 dwordx2 plain cached loads (xq), NO wait ----------------------
#define ISSUE_XQ(xb, x) asm volatile( \
    "global_load_dwordx2 %0, %4, off\n\t" \
    "global_load_dwordx2 %1, %5, off\n\t" \
    "global_load_dwordx2 %2, %6, off\n\t" \
    "global_load_dwordx2 %3, %7, off" \
    : "=&v"(x[0]), "=&v"(x[1]), "=&v"(x[2]), "=&v"(x[3]) \
    : "v"(xb), "v"((xb) + 16384), "v"((xb) + 32768), "v"((xb) + 49152) \
    : "memory")

__device__ __forceinline__ void st_u32_mall(unsigned* p, unsigned v){
  asm volatile("global_store_dword %0, %1, off sc0 sc1"
               :: "v"(p), "v"(v) : "memory");
}

// ---------------- weight transpose+convert: W[k][n] f32 -> Wt[n][k] bf16 ----
__global__ __launch_bounds__(256) void k_prep(
    const float* __restrict__ w0, const float* __restrict__ w1,
    const float* __restrict__ w2, const float* __restrict__ w3,
    const float* __restrict__ w4, const float* __restrict__ w5,
    const float* __restrict__ w6, const float* __restrict__ w7,
    const float* __restrict__ w8, unsigned short* __restrict__ wt)
{
  const int z = blockIdx.z;
  const float* W = (z==0)?w0:(z==1)?w1:(z==2)?w2:(z==3)?w3:(z==4)?w4:
                   (z==5)?w5:(z==6)?w6:(z==7)?w7:w8;
  unsigned short* out = wt + (size_t)z*1024*1024;
  __shared__ float tile[64][65];
  const int k0 = blockIdx.x*64, n0 = blockIdx.y*64;
  const int tid = threadIdx.x;
  {
    const int kk = tid >> 2, nn0 = (tid & 3) * 16;
    const float* src = W + (size_t)(k0+kk)*1024 + n0 + nn0;
    #pragma unroll
    for (int j=0;j<16;j+=4){
      f32x4 v = *(const f32x4*)(src + j);
      tile[kk][nn0+j+0]=v[0]; tile[kk][nn0+j+1]=v[1];
      tile[kk][nn0+j+2]=v[2]; tile[kk][nn0+j+3]=v[3];
    }
  }
  __syncthreads();
  {
    const int nn = tid >> 2, kk0 = (tid & 3) * 16;
    ushort8_t a, b;
    #pragma unroll
    for (int j=0;j<8;++j){ a[j]=f2b(tile[kk0+j][nn]); b[j]=f2b(tile[kk0+8+j][nn]); }
    unsigned short* dst = out + (size_t)(n0+nn)*1024 + k0 + kk0;
    *(ushort8_t*)dst = a;
    *(ushort8_t*)(dst+8) = b;
  }
}

// ---------------- h0 -> hs[0] bf16 ------------------------------------------
__global__ void k_init(const float* __restrict__ h0, unsigned short* __restrict__ hs){
  const int i = blockIdx.x*256 + threadIdx.x;
  hs[i] = f2b(h0[i]);
}

// ---------------- sentinel-fill hs[1..1024] ---------------------------------
__global__ void k_fill(unsigned* __restrict__ hsw){
  const size_t i = (size_t)blockIdx.x*256 + threadIdx.x;   // 2,097,152 threads
  uint4_t v = (uint4_t){SENT, SENT, SENT, SENT};
  *(uint4_t*)(hsw + 8192 + i*4) = v;                       // slot1 starts at word 8192
}

// ---------------- x projections: xg[t][g][n][b] = x @ Wx + bx (bf16 out) ----
__global__ __launch_bounds__(256,2) void k_xproj(
    const float* __restrict__ xF, const float* __restrict__ xI,
    const float* __restrict__ xZ, const float* __restrict__ xO,
    const float* __restrict__ bF, const float* __restrict__ bI,
    const float* __restrict__ bZ, const float* __restrict__ bO,
    const unsigned short* __restrict__ Wt,   // [4][n][k] bf16
    unsigned short* __restrict__ xg)
{
  const int g  = blockIdx.z;
  const int tm = blockIdx.x, tn = blockIdx.y;
  const float* X  = (g==0)?xF:(g==1)?xI:(g==2)?xZ:xO;
  const float* Bp = (g==0)?bF:(g==1)?bI:(g==2)?bZ:bO;
  const unsigned short* Wg = Wt + (size_t)g*1024*1024;

  __shared__ unsigned short Asm[128*32];
  __shared__ unsigned short Bsm[128*32];

  const int tid  = threadIdx.x;
  const int lane = tid & 63, wv = tid >> 6;
  const int l15  = lane & 15, lg = lane >> 4;
  const int wy   = wv >> 1,  wx = wv & 1;

  const int rr = tid >> 1, kq = tid & 1;
  const int ar = tm*128 + rr;
  const int ab = ar & 15, as_ = ar >> 4;
  const float* aptr = X + ((size_t)ab*1024 + as_)*1024 + kq*16;
  const unsigned short* bp_ = Wg + (size_t)(tn*128 + rr)*1024 + kq*16;
  const int s0 = kq*2;
  unsigned short* aw0 = &Asm[rr*32 + (((s0  ) ^ (rr&3))<<3)];
  unsigned short* aw1 = &Asm[rr*32 + (((s0+1) ^ (rr&3))<<3)];
  unsigned short* bw0 = &Bsm[rr*32 + (((s0  ) ^ (rr&3))<<3)];
  unsigned short* bw1 = &Bsm[rr*32 + (((s0+1) ^ (rr&3))<<3)];

  f32x4 acc[4][4];
  #pragma unroll
  for (int m=0;m<4;++m)
    #pragma unroll
    for (int q=0;q<4;++q) acc[m][q] = (f32x4){0.f,0.f,0.f,0.f};

  for (int k0=0; k0<1024; k0+=32){
    const float* ap = aptr + k0;
    f32x4 v0 = *(const f32x4*)(ap + 0);
    f32x4 v1 = *(const f32x4*)(ap + 4);
    f32x4 v2 = *(const f32x4*)(ap + 8);
    f32x4 v3 = *(const f32x4*)(ap + 12);
    ushort8_t pa, pb;
    #pragma unroll
    for (int j=0;j<4;++j){ pa[j]=f2b(v0[j]); pa[4+j]=f2b(v1[j]); pb[j]=f2b(v2[j]); pb[4+j]=f2b(v3[j]); }
    *(ushort8_t*)aw0 = pa;
    *(ushort8_t*)aw1 = pb;
    ushort8_t q0 = *(const ushort8_t*)(bp_ + k0);
    ushort8_t q1 = *(const ushort8_t*)(bp_ + k0 + 8);
    *(ushort8_t*)bw0 = q0;
    *(ushort8_t*)bw1 = q1;
    __syncthreads();

    short8 af[4], bf_[4];
    #pragma unroll
    for (int m=0;m<4;++m){
      int row = wy*64 + m*16 + l15;
      af[m] = *(const short8*)&Asm[row*32 + ((lg ^ (row&3))<<3)];
    }
    #pragma unroll
    for (int q=0;q<4;++q){
      int row = wx*64 + q*16 + l15;
      bf_[q] = *(const short8*)&Bsm[row*32 + ((lg ^ (row&3))<<3)];
    }
    #pragma unroll
    for (int m=0;m<4;++m)
      #pragma unroll
      for (int q=0;q<4;++q)
        acc[m][q] = __builtin_amdgcn_mfma_f32_16x16x32_bf16(af[m], bf_[q], acc[m][q], 0,0,0);
    __syncthreads();
  }

  #pragma unroll
  for (int m=0;m<4;++m){
    const int t = tm*8 + wy*4 + m;
    #pragma unroll
    for (int q=0;q<4;++q){
      const int n = tn*128 + wx*64 + q*16 + l15;
      const float bias = Bp[n];
      f32x4 v = acc[m][q];
      ushort4_t pk;
      #pragma unroll
      for (int r=0;r<4;++r) pk[r] = f2b(v[r] + bias);
      *(ushort4_t*)(xg + (size_t)((t*4+g)*1024 + n)*16 + lg*4) = pk;
    }
  }
}

// ---------------- persistent recurrence --------------------------------------
// 32 WGs x 512 threads (8 waves). WG wg owns cols [wg*32,+32); wave wv holds
// K-slice [wv*128,+128) in 128 weight VGPRs (4 gates x 2 col-groups x 4 chunks).
// Spec-load h(t) at step start (4 dwordx4/lane, sc0sc1); chunk-predicated
// sentinel retry. Component-plane LDS reduce across 8 waves; each thread gates
// exactly one (row,col): e=wv&1 (col group), comp=wv>>1 (row within lg group).
__global__ __launch_bounds__(512,1) void k_recur(
    const unsigned short* __restrict__ WtR,   // [4][1024 n][1024 k] bf16 (Fh,Ih,Zh,Oh)
    const float* __restrict__ bfh, const float* __restrict__ bih,
    const float* __restrict__ bzh, const float* __restrict__ boh,
    const float* __restrict__ c0,
    const unsigned short* __restrict__ xg,
    unsigned short* __restrict__ hs,
    float* __restrict__ oc, float* __restrict__ oh)
{
  const int wg   = blockIdx.x;          // 0..31
  const int tid  = threadIdx.x;
  const int wv   = tid >> 6, lane = tid & 63;
  const int l15  = lane & 15, lg = lane >> 4;
  const int n0   = wg*32;
  const int e    = wv & 1;              // col-group this thread gates
  const int cm   = wv >> 1;            // row-component this thread gates
  const int col  = n0 + e*16 + l15;     // gated column
  const int row  = lg*4 + cm;           // gated batch row
  const int sh   = cm * 16;             // component-extract shift for xq words

  // register-resident recurrent weights: wave wv's K-slice, both col-groups
  short8 wf[4][2][4];
  #pragma unroll
  for (int g=0; g<4; ++g)
    #pragma unroll
    for (int ee=0; ee<2; ++ee){
      const unsigned short* wp = WtR + (size_t)g*1048576
                               + (size_t)(n0 + ee*16 + l15)*1024 + wv*128 + lg*8;
      #pragma unroll
      for (int c=0; c<4; ++c)
        wf[g][ee][c] = *(const short8*)(wp + c*32);
    }

  // gating state: single (row, col) per thread
  float cst = c0[(size_t)row*1024 + col];
  float bias0 = bfh[col], bias1 = bih[col], bias2 = bzh[col], bias3 = boh[col];

  // partials as component planes: [pb][wave][gate][e][comp][lane] (128 KB)
  __shared__ float part[2][8][4][2][4][64];

  unsigned* hsw = (unsigned*)hs;
  const int koff = l15*1024 + wv*128 + lg*8;   // element offset within a t-slot

  short8 a[4];
  short4_t xq[4], xqn[4];

  // ---- prologue: xq(0) ----
  {
    const unsigned short* xb = xg + ((size_t)col)*16 + lg*4;
    ISSUE_XQ(xb, xq);
    asm volatile("s_waitcnt vmcnt(0)" ::: "memory");
    __builtin_amdgcn_sched_barrier(0);
  }

  float hv = 0.f;
  for (int t=0; t<1024; ++t){
    // 1. spec-load h(t) + prefetch xq(t+1); single wait
    const unsigned short* hp = hs + (size_t)t*16384 + koff;
    ISSUE_H4(hp, a);
    {
      const unsigned short* xb = xg + ((size_t)(t+1)*4096 + col)*16 + lg*4;
      ISSUE_XQ(xb, xqn);
    }
    asm volatile("s_waitcnt vmcnt(0)" ::: "memory");
    __builtin_amdgcn_sched_barrier(0);

    // 2. chunk-predicated sentinel retry
    {
      bool bad[4]; bool any = false;
      #pragma unroll
      for (int c=0;c<4;++c){
        uint4_t q = __builtin_bit_cast(uint4_t, a[c]);
        bad[c] = (q[0]==SENT)||(q[1]==SENT)||(q[2]==SENT)||(q[3]==SENT);
        any = any | bad[c];
      }
      while (__any(any)){
        __builtin_amdgcn_s_sleep(1);
        #pragma unroll
        for (int c=0;c<4;++c)
          if (bad[c])
            asm volatile("global_load_dwordx4 %0, %1, off sc0 sc1"
                         : "+v"(a[c]) : "v"(hp + c*32) : "memory");
        asm volatile("s_waitcnt vmcnt(0)" ::: "memory");
        __builtin_amdgcn_sched_barrier(0);
        any = false;
        #pragma unroll
        for (int c=0;c<4;++c){
          uint4_t q = __builtin_bit_cast(uint4_t, a[c]);
          bad[c] = (q[0]==SENT)||(q[1]==SENT)||(q[2]==SENT)||(q[3]==SENT);
          any = any | bad[c];
        }
      }
    }

    // 3. MFMA: 4 gates x 2 col-groups x 4 K-chunks (8 chains of length 4)
    f32x4 acc[4][2];
    #pragma unroll
    for (int g=0;g<4;++g){ acc[g][0]=(f32x4){0,0,0,0}; acc[g][1]=(f32x4){0,0,0,0}; }
    #pragma unroll
    for (int c=0;c<4;++c)
      #pragma unroll
      for (int g=0;g<4;++g){
        acc[g][0] = __builtin_amdgcn_mfma_f32_16x16x32_bf16(a[c], wf[g][0][c], acc[g][0], 0,0,0);
        acc[g][1] = __builtin_amdgcn_mfma_f32_16x16x32_bf16(a[c], wf[g][1][c], acc[g][1], 0,0,0);
      }

    // 4. partial store (component planes) + raw barrier (no VMEM drain)
    const int pb = t & 1;
    #pragma unroll
    for (int g=0;g<4;++g)
      #pragma unroll
      for (int ee=0;ee<2;++ee)
        #pragma unroll
        for (int c2=0;c2<4;++c2)
          part[pb][wv][g][ee][c2][lane] = acc[g][ee][c2];
    asm volatile("s_waitcnt lgkmcnt(0)" ::: "memory");
    __builtin_amdgcn_s_barrier();

    // 5. reduce across the 8 K-slice waves for this thread's (row, col)
    float rg[4];
    #pragma unroll
    for (int g=0;g<4;++g){
      float s0 = part[pb][0][g][e][cm][lane] + part[pb][1][g][e][cm][lane];
      float s1 = part[pb][2][g][e][cm][lane] + part[pb][3][g][e][cm][lane];
      float s2 = part[pb][4][g][e][cm][lane] + part[pb][5][g][e][cm][lane];
      float s3 = part[pb][6][g][e][cm][lane] + part[pb][7][g][e][cm][lane];
      rg[g] = (s0 + s1) + (s2 + s3);
    }

    // 6. gate the single (row, col)
    {
      float pf = rg[0] + b2f((unsigned short)(__builtin_bit_cast(unsigned long long, xq[0]) >> sh)) + bias0;
      float pi = rg[1] + b2f((unsigned short)(__builtin_bit_cast(unsigned long long, xq[1]) >> sh)) + bias1;
      float pz = rg[2] + b2f((unsigned short)(__builtin_bit_cast(unsigned long long, xq[2]) >> sh)) + bias2;
      float po = rg[3] + b2f((unsigned short)(__builtin_bit_cast(unsigned long long, xq[3]) >> sh)) + bias3;
      float fg = sigm(pf), ig = sigm(pi), zg = tanh_(pz), og = sigm(po);
      float cn = fg*cst + ig*zg;
      cst = cn;
      hv = og * tanh_(cn);
    }

    // 7. pack bf16 pairs across lane^1 (cols col/col^1, same row); even store
    {
      unsigned m  = (unsigned)f2b(hv);
      unsigned nb = (unsigned)__shfl_xor(m, 1);
      if ((l15 & 1) == 0){
        unsigned* pw = hsw + (size_t)(t+1)*8192 + (size_t)row*512 + (col >> 1);
        st_u32_mall(pw, m | (nb << 16));
      }
    }

    // 8. rotate xq pipeline
    #pragma unroll
    for (int g=0; g<4; ++g) xq[g] = xqn[g];
  }

  // final state: each thread owns one (row, col)
  oc[(size_t)row*1024 + col] = cst;
  oh[(size_t)row*1024 + col] = hv;
}

// ---------------- post projection: y[b][s][n] = hs[1..] @ Wpost + bpost -----
__global__ __launch_bounds__(256,2) void k_post(
    const unsigned short* __restrict__ hs,
    const unsigned short* __restrict__ Wt,   // post slice at +4M
    const float* __restrict__ bpost,
    float* __restrict__ y)
{
  const int tm = blockIdx.x, tn = blockIdx.y;
  __shared__ unsigned short Asm[128*32];
  __shared__ unsigned short Bsm[128*32];

  const int tid  = threadIdx.x;
  const int lane = tid & 63, wv = tid >> 6;
  const int l15  = lane & 15, lg = lane >> 4;
  const int wy   = wv >> 1,  wx = wv & 1;

  const int rr = tid >> 1, kq = tid & 1;
  const unsigned short* aptr = hs + 16384 + (size_t)(tm*128 + rr)*1024 + kq*16;
  const unsigned short* bp_  = Wt + (size_t)4*1024*1024 + (size_t)(tn*128 + rr)*1024 + kq*16;
  const int s0 = kq*2;
  unsigned short* aw0 = &Asm[rr*32 + (((s0  ) ^ (rr&3))<<3)];
  unsigned short* aw1 = &Asm[rr*32 + (((s0+1) ^ (rr&3))<<3)];
  unsigned short* bw0 = &Bsm[rr*32 + (((s0  ) ^ (rr&3))<<3)];
  unsigned short* bw1 = &Bsm[rr*32 + (((s0+1) ^ (rr&3))<<3)];

  f32x4 acc[4][4];
  #pragma unroll
  for (int m=0;m<4;++m)
    #pragma unroll
    for (int q=0;q<4;++q) acc[m][q] = (f32x4){0.f,0.f,0.f,0.f};

  for (int k0=0; k0<1024; k0+=32){
    ushort8_t a0 = *(const ushort8_t*)(aptr + k0);
    ushort8_t a1 = *(const ushort8_t*)(aptr + k0 + 8);
    *(ushort8_t*)aw0 = a0;
    *(ushort8_t*)aw1 = a1;
    ushort8_t q0 = *(const ushort8_t*)(bp_ + k0);
    ushort8_t q1 = *(const ushort8_t*)(bp_ + k0 + 8);
    *(ushort8_t*)bw0 = q0;
    *(ushort8_t*)bw1 = q1;
    __syncthreads();

    short8 af[4], bf_[4];
    #pragma unroll
    for (int m=0;m<4;++m){
      int row = wy*64 + m*16 + l15;
      af[m] = *(const short8*)&Asm[row*32 + ((lg ^ (row&3))<<3)];
    }
    #pragma unroll
    for (int q=0;q<4;++q){
      int row = wx*64 + q*16 + l15;
      bf_[q] = *(const short8*)&Bsm[row*32 + ((lg ^ (row&3))<<3)];
    }
    #pragma unroll
    for (int m=0;m<4;++m)
      #pragma unroll
      for (int q=0;q<4;++q)
        acc[m][q] = __builtin_amdgcn_mfma_f32_16x16x32_bf16(af[m], bf_[q], acc[m][q], 0,0,0);
    __syncthreads();
  }

  #pragma unroll
  for (int m=0;m<4;++m){
    const int s = tm*8 + wy*4 + m;
    #pragma unroll
    for (int q=0;q<4;++q){
      const int n = tn*128 + wx*64 + q*16 + l15;
      const float bias = bpost[n];
      f32x4 v = acc[m][q];
      #pragma unroll
      for (int r=0;r<4;++r){
        const int b = lg*4 + r;
        y[((size_t)b << 20) + ((size_t)s << 10) + n] = v[r] + bias;
      }
    }
  }
}

extern "C" void kernel_launch(void* const* d_in, const int* in_sizes, int n_in,
                              void* d_out, int out_size, void* d_ws, size_t ws_size,
                              hipStream_t stream)
{
  const float* f_in = (const float*)d_in[0];
  const float* i_in = (const float*)d_in[1];
  const float* z_in = (const float*)d_in[2];
  const float* o_in = (const float*)d_in[3];
  const float* c0   = (const float*)d_in[4];
  const float* h0   = (const float*)d_in[5];
  const float* W_Fx = (const float*)d_in[6];  const float* b_Fx = (const float*)d_in[7];
  const float* W_Ix = (const float*)d_in[8];  const float* b_Ix = (const float*)d_in[9];
  const float* W_Zx = (const float*)d_in[10]; const float* b_Zx = (const float*)d_in[11];
  const float* W_Ox = (const float*)d_in[12]; const float* b_Ox = (const float*)d_in[13];
  const float* W_Fh = (const float*)d_in[14]; const float* b_Fh = (const float*)d_in[15];
  const float* W_Ih = (const float*)d_in[16]; const float* b_Ih = (const float*)d_in[17];
  const float* W_Zh = (const float*)d_in[18]; const float* b_Zh = (const float*)d_in[19];
  const float* W_Oh = (const float*)d_in[20]; const float* b_Oh = (const float*)d_in[21];
  const float* W_post = (const float*)d_in[22]; const float* b_post = (const float*)d_in[23];

  char* ws = (char*)d_ws;
  unsigned short* xg    = (unsigned short*)(ws);
  unsigned short* hs    = (unsigned short*)(ws + XG_BYTES);
  unsigned short* wt    = (unsigned short*)(ws + WT_OFF);

  float* y  = (float*)d_out;
  float* oc = y + 16777216;   // 16*1024*1024
  float* oh = oc + 16384;

  k_prep<<<dim3(16,16,9), 256, 0, stream>>>(W_Fx, W_Ix, W_Zx, W_Ox, W_post,
                                            W_Fh, W_Ih, W_Zh, W_Oh, wt);
  k_init<<<64, 256, 0, stream>>>(h0, hs);
  k_fill<<<8192, 256, 0, stream>>>((unsigned*)hs);
  k_xproj<<<dim3(128,8,4), 256, 0, stream>>>(f_in, i_in, z_in, o_in,
                                             b_Fx, b_Ix, b_Zx, b_Ox, wt, xg);
  k_recur<<<32, 512, 0, stream>>>(wt + (size_t)5*1024*1024,
                                  b_Fh, b_Ih, b_Zh, b_Oh,
                                  c0, xg, hs, oc, oh);
  k_post<<<dim3(128,8), 256, 0, stream>>>(hs, wt, b_post, y);
}

// Round 10
// 3727.980 us; speedup vs baseline: 1.2063x; 1.1645x over previous
//
#include <hip/hip_runtime.h>
#include <stdint.h>
#include <stddef.h>

typedef __attribute__((ext_vector_type(8))) short short8;
typedef __attribute__((ext_vector_type(4))) short short4_t;
typedef __attribute__((ext_vector_type(8))) unsigned short ushort8_t;
typedef __attribute__((ext_vector_type(4))) unsigned short ushort4_t;
typedef __attribute__((ext_vector_type(4))) float f32x4;
typedef __attribute__((ext_vector_type(4))) unsigned uint4_t;

// workspace layout (bytes)
#define XG_BYTES  (134217728ull)          // xg: [1024 t][4 g][1024 n][16 b] bf16
#define HS_BYTES  (33587200ull)           // hs: [1025 t][16 b][1024 k] bf16
#define PAD_OFF   (XG_BYTES + HS_BYTES)   // (unused, keeps offsets)
#define WT_OFF    (PAD_OFF + 32768ull)    // Wt: [9][1024 n][1024 k] bf16

#define SENT 0x7FC07FC0u                  // bf16 NaN pair — h is finite, never equals this

__device__ __forceinline__ unsigned short f2b(float f){
  unsigned u = __builtin_bit_cast(unsigned, f);
  u += 0x7fffu + ((u >> 16) & 1u);
  return (unsigned short)(u >> 16);
}
__device__ __forceinline__ float b2f(unsigned short b){
  unsigned u = ((unsigned)b) << 16;
  return __builtin_bit_cast(float, u);
}
__device__ __forceinline__ float sigm(float x){ return 1.0f / (1.0f + __expf(-x)); }
__device__ __forceinline__ float tanh_(float x){ return 2.0f / (1.0f + __expf(-2.0f*x)) - 1.0f; }

// ---- PLAIN cached 8x dwordx4 bulk load (L2-allocating, XCD-shared) --------
__device__ __forceinline__ void ld_h8_plain(const unsigned short* p, short8* a){
  asm volatile(
    "global_load_dwordx4 %0, %8, off\n\t"
    "global_load_dwordx4 %1, %8, off offset:64\n\t"
    "global_load_dwordx4 %2, %8, off offset:128\n\t"
    "global_load_dwordx4 %3, %8, off offset:192\n\t"
    "global_load_dwordx4 %4, %8, off offset:256\n\t"
    "global_load_dwordx4 %5, %8, off offset:320\n\t"
    "global_load_dwordx4 %6, %8, off offset:384\n\t"
    "global_load_dwordx4 %7, %8, off offset:448\n\t"
    "s_waitcnt vmcnt(0)"
    : "=&v"(a[0]), "=&v"(a[1]), "=&v"(a[2]), "=&v"(a[3]),
      "=&v"(a[4]), "=&v"(a[5]), "=&v"(a[6]), "=&v"(a[7])
    : "v"(p) : "memory");
}
__device__ __forceinline__ void st_u32_mall(unsigned* p, unsigned v){
  asm volatile("global_store_dword %0, %1, off sc0 sc1"
               :: "v"(p), "v"(v) : "memory");
}

// ---------------- weight transpose+convert: W[k][n] f32 -> Wt[n][k] bf16 ----
__global__ __launch_bounds__(256) void k_prep(
    const float* __restrict__ w0, const float* __restrict__ w1,
    const float* __restrict__ w2, const float* __restrict__ w3,
    const float* __restrict__ w4, const float* __restrict__ w5,
    const float* __restrict__ w6, const float* __restrict__ w7,
    const float* __restrict__ w8, unsigned short* __restrict__ wt)
{
  const int z = blockIdx.z;
  const float* W = (z==0)?w0:(z==1)?w1:(z==2)?w2:(z==3)?w3:(z==4)?w4:
                   (z==5)?w5:(z==6)?w6:(z==7)?w7:w8;
  unsigned short* out = wt + (size_t)z*1024*1024;
  __shared__ float tile[64][65];
  const int k0 = blockIdx.x*64, n0 = blockIdx.y*64;
  const int tid = threadIdx.x;
  {
    const int kk = tid >> 2, nn0 = (tid & 3) * 16;
    const float* src = W + (size_t)(k0+kk)*1024 + n0 + nn0;
    #pragma unroll
    for (int j=0;j<16;j+=4){
      f32x4 v = *(const f32x4*)(src + j);
      tile[kk][nn0+j+0]=v[0]; tile[kk][nn0+j+1]=v[1];
      tile[kk][nn0+j+2]=v[2]; tile[kk][nn0+j+3]=v[3];
    }
  }
  __syncthreads();
  {
    const int nn = tid >> 2, kk0 = (tid & 3) * 16;
    ushort8_t a, b;
    #pragma unroll
    for (int j=0;j<8;++j){ a[j]=f2b(tile[kk0+j][nn]); b[j]=f2b(tile[kk0+8+j][nn]); }
    unsigned short* dst = out + (size_t)(n0+nn)*1024 + k0 + kk0;
    *(ushort8_t*)dst = a;
    *(ushort8_t*)(dst+8) = b;
  }
}

// ---------------- h0 -> hs[0] bf16 (write-through: no dirty L2 lines) -------
__global__ void k_init(const float* __restrict__ h0, unsigned short* __restrict__ hs){
  const int i = blockIdx.x*256 + threadIdx.x;
  unsigned v = (unsigned)f2b(h0[i]);
  asm volatile("global_store_short %0, %1, off sc0 sc1"
               :: "v"(hs + i), "v"(v) : "memory");
}

// ---------------- sentinel-fill hs[1..1024] (write-through) -----------------
__global__ void k_fill(unsigned* __restrict__ hsw){
  const size_t i = (size_t)blockIdx.x*256 + threadIdx.x;   // 2,097,152 threads
  uint4_t v = (uint4_t){SENT, SENT, SENT, SENT};
  asm volatile("global_store_dwordx4 %0, %1, off sc0 sc1"
               :: "v"(hsw + 8192 + i*4), "v"(v) : "memory");
}

// ---------------- x projections: xg[t][g][n][b] = x @ Wx + bx (bf16 out) ----
__global__ __launch_bounds__(256,2) void k_xproj(
    const float* __restrict__ xF, const float* __restrict__ xI,
    const float* __restrict__ xZ, const float* __restrict__ xO,
    const float* __restrict__ bF, const float* __restrict__ bI,
    const float* __restrict__ bZ, const float* __restrict__ bO,
    const unsigned short* __restrict__ Wt,   // [4][n][k] bf16
    unsigned short* __restrict__ xg)
{
  const int g  = blockIdx.z;
  const int tm = blockIdx.x, tn = blockIdx.y;
  const float* X  = (g==0)?xF:(g==1)?xI:(g==2)?xZ:xO;
  const float* Bp = (g==0)?bF:(g==1)?bI:(g==2)?bZ:bO;
  const unsigned short* Wg = Wt + (size_t)g*1024*1024;

  __shared__ unsigned short Asm[128*32];
  __shared__ unsigned short Bsm[128*32];

  const int tid  = threadIdx.x;
  const int lane = tid & 63, wv = tid >> 6;
  const int l15  = lane & 15, lg = lane >> 4;
  const int wy   = wv >> 1,  wx = wv & 1;

  const int rr = tid >> 1, kq = tid & 1;
  const int ar = tm*128 + rr;
  const int ab = ar & 15, as_ = ar >> 4;
  const float* aptr = X + ((size_t)ab*1024 + as_)*1024 + kq*16;
  const unsigned short* bp_ = Wg + (size_t)(tn*128 + rr)*1024 + kq*16;
  const int s0 = kq*2;
  unsigned short* aw0 = &Asm[rr*32 + (((s0  ) ^ (rr&3))<<3)];
  unsigned short* aw1 = &Asm[rr*32 + (((s0+1) ^ (rr&3))<<3)];
  unsigned short* bw0 = &Bsm[rr*32 + (((s0  ) ^ (rr&3))<<3)];
  unsigned short* bw1 = &Bsm[rr*32 + (((s0+1) ^ (rr&3))<<3)];

  f32x4 acc[4][4];
  #pragma unroll
  for (int m=0;m<4;++m)
    #pragma unroll
    for (int q=0;q<4;++q) acc[m][q] = (f32x4){0.f,0.f,0.f,0.f};

  for (int k0=0; k0<1024; k0+=32){
    const float* ap = aptr + k0;
    f32x4 v0 = *(const f32x4*)(ap + 0);
    f32x4 v1 = *(const f32x4*)(ap + 4);
    f32x4 v2 = *(const f32x4*)(ap + 8);
    f32x4 v3 = *(const f32x4*)(ap + 12);
    ushort8_t pa, pb;
    #pragma unroll
    for (int j=0;j<4;++j){ pa[j]=f2b(v0[j]); pa[4+j]=f2b(v1[j]); pb[j]=f2b(v2[j]); pb[4+j]=f2b(v3[j]); }
    *(ushort8_t*)aw0 = pa;
    *(ushort8_t*)aw1 = pb;
    ushort8_t q0 = *(const ushort8_t*)(bp_ + k0);
    ushort8_t q1 = *(const ushort8_t*)(bp_ + k0 + 8);
    *(ushort8_t*)bw0 = q0;
    *(ushort8_t*)bw1 = q1;
    __syncthreads();

    short8 af[4], bf_[4];
    #pragma unroll
    for (int m=0;m<4;++m){
      int row = wy*64 + m*16 + l15;
      af[m] = *(const short8*)&Asm[row*32 + ((lg ^ (row&3))<<3)];
    }
    #pragma unroll
    for (int q=0;q<4;++q){
      int row = wx*64 + q*16 + l15;
      bf_[q] = *(const short8*)&Bsm[row*32 + ((lg ^ (row&3))<<3)];
    }
    #pragma unroll
    for (int m=0;m<4;++m)
      #pragma unroll
      for (int q=0;q<4;++q)
        acc[m][q] = __builtin_amdgcn_mfma_f32_16x16x32_bf16(af[m], bf_[q], acc[m][q], 0,0,0);
    __syncthreads();
  }

  #pragma unroll
  for (int m=0;m<4;++m){
    const int t = tm*8 + wy*4 + m;
    #pragma unroll
    for (int q=0;q<4;++q){
      const int n = tn*128 + wx*64 + q*16 + l15;
      const float bias = Bp[n];
      f32x4 v = acc[m][q];
      ushort4_t pk;
      #pragma unroll
      for (int r=0;r<4;++r) pk[r] = f2b(v[r] + bias);
      *(ushort4_t*)(xg + (size_t)((t*4+g)*1024 + n)*16 + lg*4) = pk;
    }
  }
}

// ---------------- persistent recurrence (R5 structure + XCD-shared loads) ---
// 64 WGs; WG wg owns output cols [wg*16,+16); wave wv holds K-slice [wv*256,+256)
// in 128 weight regs. Spec-load h(t) with PLAIN cached loads (8 WGs per XCD
// share one L2 fill from MALL -> 8x less coherence-point traffic). Sentinel
// detect -> chunk-predicated sc0sc1 retry (bypasses stale L2 lines). Producers
// and init/fill write hs ONLY via sc0sc1 write-through: no dirty L2 lines, so
// plain loads return correct-or-sentinel, never garbage.
__global__ __launch_bounds__(256,1) void k_recur(
    const unsigned short* __restrict__ WtR,   // [4][1024 n][1024 k] bf16 (Fh,Ih,Zh,Oh)
    const float* __restrict__ bfh, const float* __restrict__ bih,
    const float* __restrict__ bzh, const float* __restrict__ boh,
    const float* __restrict__ c0,
    const unsigned short* __restrict__ xg,
    unsigned short* __restrict__ hs,
    float* __restrict__ oc, float* __restrict__ oh)
{
  const int wg   = blockIdx.x;          // 0..63
  const int tid  = threadIdx.x;
  const int wv   = tid >> 6, lane = tid & 63;
  const int l15  = lane & 15, lg = lane >> 4;
  const int n    = wg*16 + l15;

  // register-resident recurrent weights (pre-transposed bf16, coalesced)
  short8 wf[4][8];
  #pragma unroll
  for (int g=0; g<4; ++g){
    const unsigned short* wp = WtR + (size_t)g*1048576 + (size_t)n*1024 + wv*256 + lg*8;
    #pragma unroll
    for (int c=0; c<8; ++c)
      wf[g][c] = *(const short8*)(wp + c*32);
  }

  // gating state on ALL waves (redundant, identical math -> identical values)
  float cst[4]; float bias[4];
  bias[0]=bfh[n]; bias[1]=bih[n]; bias[2]=bzh[n]; bias[3]=boh[n];
  #pragma unroll
  for (int r=0;r<4;++r) cst[r] = c0[(size_t)(lg*4+r)*1024 + n];

  __shared__ f32x4 part[2][4][4][64];   // [buf][wave][gate][lane]

  unsigned* hsw = (unsigned*)hs;
  const int koff = l15*1024 + wv*256 + lg*8;

  float hv = 0.f;
  for (int t=0; t<1024; ++t){
    // xg[t] prefetch (plain cached loads; in flight with the bulk load)
    short4_t xq[4];
    #pragma unroll
    for (int g=0; g<4; ++g)
      xq[g] = *(const short4_t*)(xg + (size_t)((t*4+g)*1024 + n)*16 + lg*4);

    // speculative bulk A-fragment load: PLAIN (L2-allocating, XCD-shared)
    const unsigned short* hp = hs + (size_t)t*16384 + koff;
    short8 a[8];
    ld_h8_plain(hp, a);
    // sentinel check; retry only bad 16B chunks via sc0sc1 (bypass stale L2)
    {
      bool bad[8]; bool any = false;
      #pragma unroll
      for (int c=0;c<8;++c){
        uint4_t q = __builtin_bit_cast(uint4_t, a[c]);
        bad[c] = (q[0]==SENT)||(q[1]==SENT)||(q[2]==SENT)||(q[3]==SENT);
        any = any | bad[c];
      }
      while (__any(any)){
        __builtin_amdgcn_s_sleep(1);
        #pragma unroll
        for (int c=0;c<8;++c)
          if (bad[c])
            asm volatile("global_load_dwordx4 %0, %1, off sc0 sc1"
                         : "+v"(a[c]) : "v"(hp + c*32) : "memory");
        asm volatile("s_waitcnt vmcnt(0)" ::: "memory");
        __builtin_amdgcn_sched_barrier(0);
        any = false;
        #pragma unroll
        for (int c=0;c<8;++c){
          uint4_t q = __builtin_bit_cast(uint4_t, a[c]);
          bad[c] = (q[0]==SENT)||(q[1]==SENT)||(q[2]==SENT)||(q[3]==SENT);
          any = any | bad[c];
        }
      }
    }

    f32x4 acc[4];
    #pragma unroll
    for (int g=0;g<4;++g) acc[g] = (f32x4){0.f,0.f,0.f,0.f};
    #pragma unroll
    for (int c=0;c<8;++c){
      acc[0] = __builtin_amdgcn_mfma_f32_16x16x32_bf16(a[c], wf[0][c], acc[0], 0,0,0);
      acc[1] = __builtin_amdgcn_mfma_f32_16x16x32_bf16(a[c], wf[1][c], acc[1], 0,0,0);
      acc[2] = __builtin_amdgcn_mfma_f32_16x16x32_bf16(a[c], wf[2][c], acc[2], 0,0,0);
      acc[3] = __builtin_amdgcn_mfma_f32_16x16x32_bf16(a[c], wf[3][c], acc[3], 0,0,0);
    }
    const int pb = t & 1;
    #pragma unroll
    for (int g=0;g<4;++g) part[pb][wv][g][lane] = acc[g];
    __syncthreads();   // single sync per step (double-buffered partials)

    f32x4 r_[4];
    #pragma unroll
    for (int g=0;g<4;++g){
      f32x4 s0 = part[pb][0][g][lane];
      f32x4 s1 = part[pb][1][g][lane];
      f32x4 s2 = part[pb][2][g][lane];
      f32x4 s3 = part[pb][3][g][lane];
      r_[g] = (s0 + s1) + (s2 + s3);
    }

    float hvv[4];
    // compute own row-quarter (r = wv) FIRST and store it immediately
    {
      const int r = wv;
      float pf = r_[0][r] + b2f((unsigned short)xq[0][r]) + bias[0];
      float pi = r_[1][r] + b2f((unsigned short)xq[1][r]) + bias[1];
      float pz = r_[2][r] + b2f((unsigned short)xq[2][r]) + bias[2];
      float po = r_[3][r] + b2f((unsigned short)xq[3][r]) + bias[3];
      float fg = sigm(pf), ig = sigm(pi), zg = tanh_(pz), og = sigm(po);
      float cn = fg*cst[r] + ig*zg;
      cst[r] = cn;
      hv = og * tanh_(cn);
      hvv[r] = hv;
      unsigned m  = (unsigned)f2b(hv);
      unsigned nb = (unsigned)__shfl_xor(m, 1);
      if ((l15 & 1) == 0){
        unsigned word = m | (nb << 16);
        unsigned* pw = hsw + (size_t)(t+1)*8192 + (size_t)(lg*4+wv)*512 + (n >> 1);
        st_u32_mall(pw, word);   // write-through: no dirty L2 line
      }
    }
    // remaining row-quarters (cell-state carry only)
    #pragma unroll
    for (int r=0;r<4;++r){
      if (r == wv) continue;
      float pf = r_[0][r] + b2f((unsigned short)xq[0][r]) + bias[0];
      float pi = r_[1][r] + b2f((unsigned short)xq[1][r]) + bias[1];
      float pz = r_[2][r] + b2f((unsigned short)xq[2][r]) + bias[2];
      float po = r_[3][r] + b2f((unsigned short)xq[3][r]) + bias[3];
      float fg = sigm(pf), ig = sigm(pi), zg = tanh_(pz), og = sigm(po);
      float cn = fg*cst[r] + ig*zg;
      cst[r] = cn;
      hvv[r] = og * tanh_(cn);
    }
    if (t == 1023 && wv == 0){
      #pragma unroll
      for (int r=0;r<4;++r){
        oc[(size_t)(lg*4+r)*1024 + n] = cst[r];
        oh[(size_t)(lg*4+r)*1024 + n] = hvv[r];
      }
    }
  }
}

// ---------------- post projection: y[b][s][n] = hs[1..] @ Wpost + bpost -----
__global__ __launch_bounds__(256,2) void k_post(
    const unsigned short* __restrict__ hs,
    const unsigned short* __restrict__ Wt,   // post slice at +4M
    const float* __restrict__ bpost,
    float* __restrict__ y)
{
  const int tm = blockIdx.x, tn = blockIdx.y;
  __shared__ unsigned short Asm[128*32];
  __shared__ unsigned short Bsm[128*32];

  const int tid  = threadIdx.x;
  const int lane = tid & 63, wv = tid >> 6;
  const int l15  = lane & 15, lg = lane >> 4;
  const int wy   = wv >> 1,  wx = wv & 1;

  const int rr = tid >> 1, kq = tid & 1;
  const unsigned short* aptr = hs + 16384 + (size_t)(tm*128 + rr)*1024 + kq*16;
  const unsigned short* bp_  = Wt + (size_t)4*1024*1024 + (size_t)(tn*128 + rr)*1024 + kq*16;
  const int s0 = kq*2;
  unsigned short* aw0 = &Asm[rr*32 + (((s0  ) ^ (rr&3))<<3)];
  unsigned short* aw1 = &Asm[rr*32 + (((s0+1) ^ (rr&3))<<3)];
  unsigned short* bw0 = &Bsm[rr*32 + (((s0  ) ^ (rr&3))<<3)];
  unsigned short* bw1 = &Bsm[rr*32 + (((s0+1) ^ (rr&3))<<3)];

  f32x4 acc[4][4];
  #pragma unroll
  for (int m=0;m<4;++m)
    #pragma unroll
    for (int q=0;q<4;++q) acc[m][q] = (f32x4){0.f,0.f,0.f,0.f};

  for (int k0=0; k0<1024; k0+=32){
    ushort8_t a0 = *(const ushort8_t*)(aptr + k0);
    ushort8_t a1 = *(const ushort8_t*)(aptr + k0 + 8);
    *(ushort8_t*)aw0 = a0;
    *(ushort8_t*)aw1 = a1;
    ushort8_t q0 = *(const ushort8_t*)(bp_ + k0);
    ushort8_t q1 = *(const ushort8_t*)(bp_ + k0 + 8);
    *(ushort8_t*)bw0 = q0;
    *(ushort8_t*)bw1 = q1;
    __syncthreads();

    short8 af[4], bf_[4];
    #pragma unroll
    for (int m=0;m<4;++m){
      int row = wy*64 + m*16 + l15;
      af[m] = *(const short8*)&Asm[row*32 + ((lg ^ (row&3))<<3)];
    }
    #pragma unroll
    for (int q=0;q<4;++q){
      int row = wx*64 + q*16 + l15;
      bf_[q] = *(const short8*)&Bsm[row*32 + ((lg ^ (row&3))<<3)];
    }
    #pragma unroll
    for (int m=0;m<4;++m)
      #pragma unroll
      for (int q=0;q<4;++q)
        acc[m][q] = __builtin_amdgcn_mfma_f32_16x16x32_bf16(af[m], bf_[q], acc[m][q], 0,0,0);
    __syncthreads();
  }

  #pragma unroll
  for (int m=0;m<4;++m){
    const int s = tm*8 + wy*4 + m;
    #pragma unroll
    for (int q=0;q<4;++q){
      const int n = tn*128 + wx*64 + q*16 + l15;
      const float bias = bpost[n];
      f32x4 v = acc[m][q];
      #pragma unroll
      for (int r=0;r<4;++r){
        const int b = lg*4 + r;
        y[((size_t)b << 20) + ((size_t)s << 10) + n] = v[r] + bias;
      }
    }
  }
}

extern "C" void kernel_launch(void* const* d_in, const int* in_sizes, int n_in,
                              void* d_out, int out_size, void* d_ws, size_t ws_size,
                              hipStream_t stream)
{
  const float* f_in = (const float*)d_in[0];
  const float* i_in = (const float*)d_in[1];
  const float* z_in = (const float*)d_in[2];
  const float* o_in = (const float*)d_in[3];
  const float* c0   = (const float*)d_in[4];
  const float* h0   = (const float*)d_in[5];
  const float* W_Fx = (const float*)d_in[6];  const float* b_Fx = (const float*)d_in[7];
  const float* W_Ix = (const float*)d_in[8];  const float* b_Ix = (const float*)d_in[9];
  const float* W_Zx = (const float*)d_in[10]; const float* b_Zx = (const float*)d_in[11];
  const float* W_Ox = (const float*)d_in[12]; const float* b_Ox = (const float*)d_in[13];
  const float* W_Fh = (const float*)d_in[14]; const float* b_Fh = (const float*)d_in[15];
  const float* W_Ih = (const float*)d_in[16]; const float* b_Ih = (const float*)d_in[17];
  const float* W_Zh = (const float*)d_in[18]; const float* b_Zh = (const float*)d_in[19];
  const float* W_Oh = (const float*)d_in[20]; const float* b_Oh = (const float*)d_in[21];
  const float* W_post = (const float*)d_in[22]; const float* b_post = (const float*)d_in[23];

  char* ws = (char*)d_ws;
  unsigned short* xg    = (unsigned short*)(ws);
  unsigned short* hs    = (unsigned short*)(ws + XG_BYTES);
  unsigned short* wt    = (unsigned short*)(ws + WT_OFF);

  float* y  = (float*)d_out;
  float* oc = y + 16777216;   // 16*1024*1024
  float* oh = oc + 16384;

  k_prep<<<dim3(16,16,9), 256, 0, stream>>>(W_Fx, W_Ix, W_Zx, W_Ox, W_post,
                                            W_Fh, W_Ih, W_Zh, W_Oh, wt);
  k_init<<<64, 256, 0, stream>>>(h0, hs);
  k_fill<<<8192, 256, 0, stream>>>((unsigned*)hs);
  k_xproj<<<dim3(128,8,4), 256, 0, stream>>>(f_in, i_in, z_in, o_in,
                                             b_Fx, b_Ix, b_Zx, b_Ox, wt, xg);
  k_recur<<<64, 256, 0, stream>>>(wt + (size_t)5*1024*1024,
                                  b_Fh, b_Ih, b_Zh, b_Oh,
                                  c0, xg, hs, oc, oh);
  k_post<<<dim3(128,8), 256, 0, stream>>>(hs, wt, b_post, y);
}

// Round 11
// 3555.709 us; speedup vs baseline: 1.2648x; 1.0484x over previous
//
#include <hip/hip_runtime.h>
#include <stdint.h>
#include <stddef.h>

typedef __attribute__((ext_vector_type(8))) short short8;
typedef __attribute__((ext_vector_type(4))) short short4_t;
typedef __attribute__((ext_vector_type(8))) unsigned short ushort8_t;
typedef __attribute__((ext_vector_type(4))) unsigned short ushort4_t;
typedef __attribute__((ext_vector_type(4))) float f32x4;
typedef __attribute__((ext_vector_type(4))) unsigned uint4_t;
typedef __attribute__((ext_vector_type(2))) unsigned uint2_t;

// workspace layout (bytes)
#define XG_BYTES  (134217728ull)          // xg: [1024 t][4 g][1024 n][16 b] bf16
#define HS_BYTES  (33587200ull)           // hs: [1025 t][16 b][1024 k] bf16
#define PAD_OFF   (XG_BYTES + HS_BYTES)
#define WT_OFF    (PAD_OFF + 32768ull)    // Wt: [9][1024 n][1024 k] bf16

#define SENT 0x7FC07FC0u                  // bf16 NaN pair — finite data never equals this

__device__ __forceinline__ unsigned short f2b(float f){
  unsigned u = __builtin_bit_cast(unsigned, f);
  u += 0x7fffu + ((u >> 16) & 1u);
  return (unsigned short)(u >> 16);
}
__device__ __forceinline__ float b2f(unsigned short b){
  unsigned u = ((unsigned)b) << 16;
  return __builtin_bit_cast(float, u);
}
__device__ __forceinline__ float sigm(float x){ return 1.0f / (1.0f + __expf(-x)); }
__device__ __forceinline__ float tanh_(float x){ return 2.0f / (1.0f + __expf(-2.0f*x)) - 1.0f; }

// ---- PLAIN cached 8x dwordx4 bulk load (L2-allocating, XCD-shared) --------
__device__ __forceinline__ void ld_h8_plain(const unsigned short* p, short8* a){
  asm volatile(
    "global_load_dwordx4 %0, %8, off\n\t"
    "global_load_dwordx4 %1, %8, off offset:64\n\t"
    "global_load_dwordx4 %2, %8, off offset:128\n\t"
    "global_load_dwordx4 %3, %8, off offset:192\n\t"
    "global_load_dwordx4 %4, %8, off offset:256\n\t"
    "global_load_dwordx4 %5, %8, off offset:320\n\t"
    "global_load_dwordx4 %6, %8, off offset:384\n\t"
    "global_load_dwordx4 %7, %8, off offset:448\n\t"
    "s_waitcnt vmcnt(0)"
    : "=&v"(a[0]), "=&v"(a[1]), "=&v"(a[2]), "=&v"(a[3]),
      "=&v"(a[4]), "=&v"(a[5]), "=&v"(a[6]), "=&v"(a[7])
    : "v"(p) : "memory");
}
__device__ __forceinline__ void st_u32_mall(unsigned* p, unsigned v){
  asm volatile("global_store_dword %0, %1, off sc0 sc1"
               :: "v"(p), "v"(v) : "memory");
}

// ---------------- weight transpose+convert: W[k][n] f32 -> Wt[n][k] bf16 ----
__global__ __launch_bounds__(256) void k_prep(
    const float* __restrict__ w0, const float* __restrict__ w1,
    const float* __restrict__ w2, const float* __restrict__ w3,
    const float* __restrict__ w4, const float* __restrict__ w5,
    const float* __restrict__ w6, const float* __restrict__ w7,
    const float* __restrict__ w8, unsigned short* __restrict__ wt)
{
  const int z = blockIdx.z;
  const float* W = (z==0)?w0:(z==1)?w1:(z==2)?w2:(z==3)?w3:(z==4)?w4:
                   (z==5)?w5:(z==6)?w6:(z==7)?w7:w8;
  unsigned short* out = wt + (size_t)z*1024*1024;
  __shared__ float tile[64][65];
  const int k0 = blockIdx.x*64, n0 = blockIdx.y*64;
  const int tid = threadIdx.x;
  {
    const int kk = tid >> 2, nn0 = (tid & 3) * 16;
    const float* src = W + (size_t)(k0+kk)*1024 + n0 + nn0;
    #pragma unroll
    for (int j=0;j<16;j+=4){
      f32x4 v = *(const f32x4*)(src + j);
      tile[kk][nn0+j+0]=v[0]; tile[kk][nn0+j+1]=v[1];
      tile[kk][nn0+j+2]=v[2]; tile[kk][nn0+j+3]=v[3];
    }
  }
  __syncthreads();
  {
    const int nn = tid >> 2, kk0 = (tid & 3) * 16;
    ushort8_t a, b;
    #pragma unroll
    for (int j=0;j<8;++j){ a[j]=f2b(tile[kk0+j][nn]); b[j]=f2b(tile[kk0+8+j][nn]); }
    unsigned short* dst = out + (size_t)(n0+nn)*1024 + k0 + kk0;
    *(ushort8_t*)dst = a;
    *(ushort8_t*)(dst+8) = b;
  }
}

// ---------------- h0 -> hs[0] bf16 (write-through) ---------------------------
__global__ void k_init(const float* __restrict__ h0, unsigned short* __restrict__ hs){
  const int i = blockIdx.x*256 + threadIdx.x;
  unsigned v = (unsigned)f2b(h0[i]);
  asm volatile("global_store_short %0, %1, off sc0 sc1"
               :: "v"(hs + i), "v"(v) : "memory");
}

// ---------------- sentinel-fill xg (all) + hs[1..1024] (write-through) -------
__global__ void k_fill(unsigned* __restrict__ xgw, unsigned* __restrict__ hsw){
  const size_t i = (size_t)blockIdx.x*256 + threadIdx.x;   // 10,485,760 threads
  uint4_t v = (uint4_t){SENT, SENT, SENT, SENT};
  if (i < 8388608ull){
    asm volatile("global_store_dwordx4 %0, %1, off sc0 sc1"
                 :: "v"(xgw + i*4), "v"(v) : "memory");
  } else {
    asm volatile("global_store_dwordx4 %0, %1, off sc0 sc1"
                 :: "v"(hsw + 8192 + (i - 8388608ull)*4), "v"(v) : "memory");
  }
}

// ---------------- fused mega-kernel ------------------------------------------
// WGs 0..63:   persistent recurrence (R10 core; xq now sentinel-gated).
// WGs 64..255: xproj tiles (tm-major), sc0sc1 writes to xg; then post tiles
//              (tm-major), A-staging sentinel-gated on hs with s_sleep backoff.
__global__ __launch_bounds__(256,1) void k_mega(
    const float* __restrict__ xF, const float* __restrict__ xI,
    const float* __restrict__ xZ, const float* __restrict__ xO,
    const float* __restrict__ bF, const float* __restrict__ bI,
    const float* __restrict__ bZ, const float* __restrict__ bO,
    const unsigned short* __restrict__ wt,   // [9][1024][1024] bf16
    const float* __restrict__ bfh, const float* __restrict__ bih,
    const float* __restrict__ bzh, const float* __restrict__ boh,
    const float* __restrict__ c0,
    unsigned short* __restrict__ xg,
    unsigned short* __restrict__ hs,
    const float* __restrict__ bpost,
    float* __restrict__ y,
    float* __restrict__ oc, float* __restrict__ oh)
{
  __shared__ __align__(16) char smem[32768];
  const int tid  = threadIdx.x;
  const int lane = tid & 63, wv = tid >> 6;
  const int l15  = lane & 15, lg = lane >> 4;

  if (blockIdx.x < 64){
    // ==================== recurrence (R10 core) ====================
    typedef f32x4 PartT[4][4][64];
    PartT* part = (PartT*)smem;              // part[2][4][4][64]

    const unsigned short* WtR = wt + (size_t)5*1048576;
    const int wg = blockIdx.x;
    const int n  = wg*16 + l15;

    short8 wf[4][8];
    #pragma unroll
    for (int g=0; g<4; ++g){
      const unsigned short* wp = WtR + (size_t)g*1048576 + (size_t)n*1024 + wv*256 + lg*8;
      #pragma unroll
      for (int c=0; c<8; ++c)
        wf[g][c] = *(const short8*)(wp + c*32);
    }

    float cst[4]; float bias[4];
    bias[0]=bfh[n]; bias[1]=bih[n]; bias[2]=bzh[n]; bias[3]=boh[n];
    #pragma unroll
    for (int r=0;r<4;++r) cst[r] = c0[(size_t)(lg*4+r)*1024 + n];

    unsigned* hsw = (unsigned*)hs;
    const int koff = l15*1024 + wv*256 + lg*8;

    float hv = 0.f;
    for (int t=0; t<1024; ++t){
      // xg[t] loads (plain, in flight with bulk load); sentinel-gated below
      short4_t xq[4];
      {
        const unsigned short* xb = xg + (size_t)((t*4)*1024 + n)*16 + lg*4;
        asm volatile(
          "global_load_dwordx2 %0, %4, off\n\t"
          "global_load_dwordx2 %1, %5, off\n\t"
          "global_load_dwordx2 %2, %6, off\n\t"
          "global_load_dwordx2 %3, %7, off"
          : "=&v"(xq[0]), "=&v"(xq[1]), "=&v"(xq[2]), "=&v"(xq[3])
          : "v"(xb), "v"(xb + 16384), "v"(xb + 32768), "v"(xb + 49152)
          : "memory");
      }

      // speculative bulk h load: PLAIN (L2 XCD-shared); sc0sc1 chunk retry
      const unsigned short* hp = hs + (size_t)t*16384 + koff;
      short8 a[8];
      ld_h8_plain(hp, a);
      {
        bool bad[8]; bool any = false;
        #pragma unroll
        for (int c=0;c<8;++c){
          uint4_t q = __builtin_bit_cast(uint4_t, a[c]);
          bad[c] = (q[0]==SENT)||(q[1]==SENT)||(q[2]==SENT)||(q[3]==SENT);
          any = any | bad[c];
        }
        while (__any(any)){
          __builtin_amdgcn_s_sleep(1);
          #pragma unroll
          for (int c=0;c<8;++c)
            if (bad[c])
              asm volatile("global_load_dwordx4 %0, %1, off sc0 sc1"
                           : "+v"(a[c]) : "v"(hp + c*32) : "memory");
          asm volatile("s_waitcnt vmcnt(0)" ::: "memory");
          __builtin_amdgcn_sched_barrier(0);
          any = false;
          #pragma unroll
          for (int c=0;c<8;++c){
            uint4_t q = __builtin_bit_cast(uint4_t, a[c]);
            bad[c] = (q[0]==SENT)||(q[1]==SENT)||(q[2]==SENT)||(q[3]==SENT);
            any = any | bad[c];
          }
        }
      }
      // xq sentinel gate (xproj runs concurrently)
      {
        bool xb_[4]; bool anyx = false;
        #pragma unroll
        for (int g=0; g<4; ++g){
          uint2_t u = __builtin_bit_cast(uint2_t, xq[g]);
          xb_[g] = (u[0]==SENT)||(u[1]==SENT);
          anyx = anyx | xb_[g];
        }
        while (__any(anyx)){
          __builtin_amdgcn_s_sleep(2);
          const unsigned short* xb = xg + (size_t)((t*4)*1024 + n)*16 + lg*4;
          #pragma unroll
          for (int g=0; g<4; ++g)
            if (xb_[g])
              asm volatile("global_load_dwordx2 %0, %1, off sc0 sc1"
                           : "+v"(xq[g]) : "v"(xb + g*16384) : "memory");
          asm volatile("s_waitcnt vmcnt(0)" ::: "memory");
          __builtin_amdgcn_sched_barrier(0);
          anyx = false;
          #pragma unroll
          for (int g=0; g<4; ++g){
            uint2_t u = __builtin_bit_cast(uint2_t, xq[g]);
            xb_[g] = (u[0]==SENT)||(u[1]==SENT);
            anyx = anyx | xb_[g];
          }
        }
      }

      f32x4 acc[4];
      #pragma unroll
      for (int g=0;g<4;++g) acc[g] = (f32x4){0.f,0.f,0.f,0.f};
      #pragma unroll
      for (int c=0;c<8;++c){
        acc[0] = __builtin_amdgcn_mfma_f32_16x16x32_bf16(a[c], wf[0][c], acc[0], 0,0,0);
        acc[1] = __builtin_amdgcn_mfma_f32_16x16x32_bf16(a[c], wf[1][c], acc[1], 0,0,0);
        acc[2] = __builtin_amdgcn_mfma_f32_16x16x32_bf16(a[c], wf[2][c], acc[2], 0,0,0);
        acc[3] = __builtin_amdgcn_mfma_f32_16x16x32_bf16(a[c], wf[3][c], acc[3], 0,0,0);
      }
      const int pb = t & 1;
      #pragma unroll
      for (int g=0;g<4;++g) part[pb][wv][g][lane] = acc[g];
      __syncthreads();

      f32x4 r_[4];
      #pragma unroll
      for (int g=0;g<4;++g){
        f32x4 s0 = part[pb][0][g][lane];
        f32x4 s1 = part[pb][1][g][lane];
        f32x4 s2 = part[pb][2][g][lane];
        f32x4 s3 = part[pb][3][g][lane];
        r_[g] = (s0 + s1) + (s2 + s3);
      }

      float hvv[4];
      {
        const int r = wv;
        float pf = r_[0][r] + b2f((unsigned short)xq[0][r]) + bias[0];
        float pi = r_[1][r] + b2f((unsigned short)xq[1][r]) + bias[1];
        float pz = r_[2][r] + b2f((unsigned short)xq[2][r]) + bias[2];
        float po = r_[3][r] + b2f((unsigned short)xq[3][r]) + bias[3];
        float fg = sigm(pf), ig = sigm(pi), zg = tanh_(pz), og = sigm(po);
        float cn = fg*cst[r] + ig*zg;
        cst[r] = cn;
        hv = og * tanh_(cn);
        hvv[r] = hv;
        unsigned m  = (unsigned)f2b(hv);
        unsigned nb = (unsigned)__shfl_xor(m, 1);
        if ((l15 & 1) == 0){
          unsigned word = m | (nb << 16);
          unsigned* pw = hsw + (size_t)(t+1)*8192 + (size_t)(lg*4+wv)*512 + (n >> 1);
          st_u32_mall(pw, word);
        }
      }
      #pragma unroll
      for (int r=0;r<4;++r){
        if (r == wv) continue;
        float pf = r_[0][r] + b2f((unsigned short)xq[0][r]) + bias[0];
        float pi = r_[1][r] + b2f((unsigned short)xq[1][r]) + bias[1];
        float pz = r_[2][r] + b2f((unsigned short)xq[2][r]) + bias[2];
        float po = r_[3][r] + b2f((unsigned short)xq[3][r]) + bias[3];
        float fg = sigm(pf), ig = sigm(pi), zg = tanh_(pz), og = sigm(po);
        float cn = fg*cst[r] + ig*zg;
        cst[r] = cn;
        hvv[r] = og * tanh_(cn);
      }
      if (t == 1023 && wv == 0){
        #pragma unroll
        for (int r=0;r<4;++r){
          oc[(size_t)(lg*4+r)*1024 + n] = cst[r];
          oh[(size_t)(lg*4+r)*1024 + n] = hvv[r];
        }
      }
    }
    return;
  }

  // ==================== xproj + post (WGs 64..255) ====================
  unsigned short* AsmB = (unsigned short*)smem;            // [128*32]
  unsigned short* BsmB = (unsigned short*)(smem + 8192);   // [128*32]
  const int wid = blockIdx.x - 64;
  const int wy = wv >> 1, wx = wv & 1;
  const int rr = tid >> 1, kq = tid & 1;
  const int s0 = kq*2;
  unsigned short* aw0 = &AsmB[rr*32 + (((s0  ) ^ (rr&3))<<3)];
  unsigned short* aw1 = &AsmB[rr*32 + (((s0+1) ^ (rr&3))<<3)];
  unsigned short* bw0 = &BsmB[rr*32 + (((s0  ) ^ (rr&3))<<3)];
  unsigned short* bw1 = &BsmB[rr*32 + (((s0+1) ^ (rr&3))<<3)];

  // ---- xproj tiles: idx = tm*32 + tn*4 + g, tm-major ----
  for (int idx = wid; idx < 4096; idx += 192){
    const int tm = idx >> 5, rmn = idx & 31, tn = rmn >> 2, g = rmn & 3;
    const float* X  = (g==0)?xF:(g==1)?xI:(g==2)?xZ:xO;
    const float* Bp = (g==0)?bF:(g==1)?bI:(g==2)?bZ:bO;
    const unsigned short* Wg = wt + (size_t)g*1048576;

    const int ar = tm*128 + rr;
    const int ab = ar & 15, as_ = ar >> 4;
    const float* aptr = X + ((size_t)ab*1024 + as_)*1024 + kq*16;
    const unsigned short* bp_ = Wg + (size_t)(tn*128 + rr)*1024 + kq*16;

    f32x4 acc[4][4];
    #pragma unroll
    for (int m=0;m<4;++m)
      #pragma unroll
      for (int q=0;q<4;++q) acc[m][q] = (f32x4){0.f,0.f,0.f,0.f};

    for (int k0=0; k0<1024; k0+=32){
      const float* ap = aptr + k0;
      f32x4 v0 = *(const f32x4*)(ap + 0);
      f32x4 v1 = *(const f32x4*)(ap + 4);
      f32x4 v2 = *(const f32x4*)(ap + 8);
      f32x4 v3 = *(const f32x4*)(ap + 12);
      ushort8_t pa, pb;
      #pragma unroll
      for (int j=0;j<4;++j){ pa[j]=f2b(v0[j]); pa[4+j]=f2b(v1[j]); pb[j]=f2b(v2[j]); pb[4+j]=f2b(v3[j]); }
      *(ushort8_t*)aw0 = pa;
      *(ushort8_t*)aw1 = pb;
      ushort8_t q0 = *(const ushort8_t*)(bp_ + k0);
      ushort8_t q1 = *(const ushort8_t*)(bp_ + k0 + 8);
      *(ushort8_t*)bw0 = q0;
      *(ushort8_t*)bw1 = q1;
      __syncthreads();

      short8 af[4], bf_[4];
      #pragma unroll
      for (int m=0;m<4;++m){
        int row = wy*64 + m*16 + l15;
        af[m] = *(const short8*)&AsmB[row*32 + ((lg ^ (row&3))<<3)];
      }
      #pragma unroll
      for (int q=0;q<4;++q){
        int row = wx*64 + q*16 + l15;
        bf_[q] = *(const short8*)&BsmB[row*32 + ((lg ^ (row&3))<<3)];
      }
      #pragma unroll
      for (int m=0;m<4;++m)
        #pragma unroll
        for (int q=0;q<4;++q)
          acc[m][q] = __builtin_amdgcn_mfma_f32_16x16x32_bf16(af[m], bf_[q], acc[m][q], 0,0,0);
      __syncthreads();
    }

    #pragma unroll
    for (int m=0;m<4;++m){
      const int t = tm*8 + wy*4 + m;
      #pragma unroll
      for (int q=0;q<4;++q){
        const int n = tn*128 + wx*64 + q*16 + l15;
        const float bias = Bp[n];
        f32x4 v = acc[m][q];
        ushort4_t pk;
        #pragma unroll
        for (int r=0;r<4;++r) pk[r] = f2b(v[r] + bias);
        uint2_t w2 = __builtin_bit_cast(uint2_t, pk);
        unsigned short* dst = xg + (size_t)((t*4+g)*1024 + n)*16 + lg*4;
        asm volatile("global_store_dwordx2 %0, %1, off sc0 sc1"
                     :: "v"(dst), "v"(w2) : "memory");
      }
    }
  }

  // ---- post tiles: idx = tm*8 + tn, tm-major; A staging gated on hs ----
  for (int idx = wid; idx < 1024; idx += 192){
    const int tm = idx >> 3, tn = idx & 7;
    const unsigned short* aptr = hs + 16384 + (size_t)(tm*128 + rr)*1024 + kq*16;
    const unsigned short* bp_  = wt + (size_t)4*1048576 + (size_t)(tn*128 + rr)*1024 + kq*16;

    f32x4 acc[4][4];
    #pragma unroll
    for (int m=0;m<4;++m)
      #pragma unroll
      for (int q=0;q<4;++q) acc[m][q] = (f32x4){0.f,0.f,0.f,0.f};

    for (int k0=0; k0<1024; k0+=32){
      ushort8_t a0, a1;
      asm volatile(
        "global_load_dwordx4 %0, %2, off\n\t"
        "global_load_dwordx4 %1, %3, off\n\t"
        "s_waitcnt vmcnt(0)"
        : "=&v"(a0), "=&v"(a1)
        : "v"(aptr + k0), "v"(aptr + k0 + 8) : "memory");
      __builtin_amdgcn_sched_barrier(0);
      {
        uint4_t q0 = __builtin_bit_cast(uint4_t, a0);
        uint4_t q1 = __builtin_bit_cast(uint4_t, a1);
        bool b0 = (q0[0]==SENT)||(q0[1]==SENT)||(q0[2]==SENT)||(q0[3]==SENT);
        bool b1 = (q1[0]==SENT)||(q1[1]==SENT)||(q1[2]==SENT)||(q1[3]==SENT);
        while (__any(b0 | b1)){
          __builtin_amdgcn_s_sleep(8);
          if (b0) asm volatile("global_load_dwordx4 %0, %1, off sc0 sc1"
                               : "+v"(a0) : "v"(aptr + k0) : "memory");
          if (b1) asm volatile("global_load_dwordx4 %0, %1, off sc0 sc1"
                               : "+v"(a1) : "v"(aptr + k0 + 8) : "memory");
          asm volatile("s_waitcnt vmcnt(0)" ::: "memory");
          __builtin_amdgcn_sched_barrier(0);
          q0 = __builtin_bit_cast(uint4_t, a0);
          q1 = __builtin_bit_cast(uint4_t, a1);
          b0 = (q0[0]==SENT)||(q0[1]==SENT)||(q0[2]==SENT)||(q0[3]==SENT);
          b1 = (q1[0]==SENT)||(q1[1]==SENT)||(q1[2]==SENT)||(q1[3]==SENT);
        }
      }
      *(ushort8_t*)aw0 = a0;
      *(ushort8_t*)aw1 = a1;
      ushort8_t q0v = *(const ushort8_t*)(bp_ + k0);
      ushort8_t q1v = *(const ushort8_t*)(bp_ + k0 + 8);
      *(ushort8_t*)bw0 = q0v;
      *(ushort8_t*)bw1 = q1v;
      __syncthreads();

      short8 af[4], bf_[4];
      #pragma unroll
      for (int m=0;m<4;++m){
        int row = wy*64 + m*16 + l15;
        af[m] = *(const short8*)&AsmB[row*32 + ((lg ^ (row&3))<<3)];
      }
      #pragma unroll
      for (int q=0;q<4;++q){
        int row = wx*64 + q*16 + l15;
        bf_[q] = *(const short8*)&BsmB[row*32 + ((lg ^ (row&3))<<3)];
      }
      #pragma unroll
      for (int m=0;m<4;++m)
        #pragma unroll
        for (int q=0;q<4;++q)
          acc[m][q] = __builtin_amdgcn_mfma_f32_16x16x32_bf16(af[m], bf_[q], acc[m][q], 0,0,0);
      __syncthreads();
    }

    #pragma unroll
    for (int m=0;m<4;++m){
      const int s = tm*8 + wy*4 + m;
      #pragma unroll
      for (int q=0;q<4;++q){
        const int n = tn*128 + wx*64 + q*16 + l15;
        const float bias = bpost[n];
        f32x4 v = acc[m][q];
        #pragma unroll
        for (int r=0;r<4;++r){
          const int b = lg*4 + r;
          y[((size_t)b << 20) + ((size_t)s << 10) + n] = v[r] + bias;
        }
      }
    }
  }
}

extern "C" void kernel_launch(void* const* d_in, const int* in_sizes, int n_in,
                              void* d_out, int out_size, void* d_ws, size_t ws_size,
                              hipStream_t stream)
{
  const float* f_in = (const float*)d_in[0];
  const float* i_in = (const float*)d_in[1];
  const float* z_in = (const float*)d_in[2];
  const float* o_in = (const float*)d_in[3];
  const float* c0   = (const float*)d_in[4];
  const float* h0   = (const float*)d_in[5];
  const float* W_Fx = (const float*)d_in[6];  const float* b_Fx = (const float*)d_in[7];
  const float* W_Ix = (const float*)d_in[8];  const float* b_Ix = (const float*)d_in[9];
  const float* W_Zx = (const float*)d_in[10]; const float* b_Zx = (const float*)d_in[11];
  const float* W_Ox = (const float*)d_in[12]; const float* b_Ox = (const float*)d_in[13];
  const float* W_Fh = (const float*)d_in[14]; const float* b_Fh = (const float*)d_in[15];
  const float* W_Ih = (const float*)d_in[16]; const float* b_Ih = (const float*)d_in[17];
  const float* W_Zh = (const float*)d_in[18]; const float* b_Zh = (const float*)d_in[19];
  const float* W_Oh = (const float*)d_in[20]; const float* b_Oh = (const float*)d_in[21];
  const float* W_post = (const float*)d_in[22]; const float* b_post = (const float*)d_in[23];

  char* ws = (char*)d_ws;
  unsigned short* xg = (unsigned short*)(ws);
  unsigned short* hs = (unsigned short*)(ws + XG_BYTES);
  unsigned short* wt = (unsigned short*)(ws + WT_OFF);

  float* y  = (float*)d_out;
  float* oc = y + 16777216;   // 16*1024*1024
  float* oh = oc + 16384;

  k_prep<<<dim3(16,16,9), 256, 0, stream>>>(W_Fx, W_Ix, W_Zx, W_Ox, W_post,
                                            W_Fh, W_Ih, W_Zh, W_Oh, wt);
  k_init<<<64, 256, 0, stream>>>(h0, hs);
  k_fill<<<40960, 256, 0, stream>>>((unsigned*)xg, (unsigned*)hs);
  k_mega<<<256, 256, 0, stream>>>(f_in, i_in, z_in, o_in,
                                  b_Fx, b_Ix, b_Zx, b_Ox,
                                  wt,
                                  b_Fh, b_Ih, b_Zh, b_Oh,
                                  c0, xg, hs, b_post, y, oc, oh);
}